// Round 11
// baseline (1119.360 us; speedup 1.0000x reference)
//
#include <hip/hip_runtime.h>
#include <math.h>

#define S_LEN 2048
#define NH 16
#define HDIM 64
#define BATCH 2
#define BHC 32          // BATCH*NH
#define KK 409          // int(2048 * (1.0 - 0.8)) per reference float math
#define DMODEL 1024

typedef __attribute__((ext_vector_type(8))) short bf16x8;   // 8 bf16 in 4 VGPRs
typedef __attribute__((ext_vector_type(4))) float f32x4;

#define SC_STRW 2056    // fp32 score row stride in words
#define P_STR   2064    // bf16 P row stride (4128 B rows, 16B-aligned)
#define T_STR   40      // bf16 LDS tile row stride for gemm (16B-aligned, 2-way free)

__device__ __forceinline__ unsigned f2ord(float f) {
    unsigned u = __float_as_uint(f);
    return (u & 0x80000000u) ? ~u : (u | 0x80000000u);
}
__device__ __forceinline__ float ord2f(unsigned v) {
    unsigned u = (v & 0x80000000u) ? (v & 0x7fffffffu) : ~v;
    return __uint_as_float(u);
}
__device__ __forceinline__ unsigned short f2bf(float f) {   // RNE
    unsigned u = __float_as_uint(f);
    u += 0x7fffu + ((u >> 16) & 1u);
    return (unsigned short)(u >> 16);
}
__device__ __forceinline__ float bf2f(unsigned short h) {
    return __uint_as_float(((unsigned)h) << 16);
}

// ---------------------------------------------------------------------------
// fp32 -> bf16 hi/lo split (vectorized float4 / ushort4), n4 = elements/4
// ---------------------------------------------------------------------------
__global__ __launch_bounds__(256)
void split32(const float* __restrict__ in, unsigned short* __restrict__ hi,
             unsigned short* __restrict__ lo, int n4)
{
    const int i = blockIdx.x * 256 + threadIdx.x;
    if (i < n4) {
        const float4 v = ((const float4*)in)[i];
        ushort4 h, l;
        h.x = f2bf(v.x); l.x = f2bf(v.x - bf2f(h.x));
        h.y = f2bf(v.y); l.y = f2bf(v.y - bf2f(h.y));
        h.z = f2bf(v.z); l.z = f2bf(v.z - bf2f(h.z));
        h.w = f2bf(v.w); l.w = f2bf(v.w - bf2f(h.w));
        ((ushort4*)hi)[i] = h;
        ((ushort4*)lo)[i] = l;
    }
}

// ---------------------------------------------------------------------------
// LDS-staged split-bf16 3-pass MFMA GEMM (unchanged from R8 — banked).
//   C[m][n] = sum_k A[m][k]*B[n][k] + bias[n]
// ---------------------------------------------------------------------------
__global__ __launch_bounds__(256)
void gemm_mfma(const unsigned short* __restrict__ Ah, const unsigned short* __restrict__ Al,
               const unsigned short* __restrict__ Bh, const unsigned short* __restrict__ Bl,
               const float* __restrict__ bias, void* __restrict__ out0,
               void* __restrict__ out1, int mode)
{
    __shared__ __align__(16) unsigned short sAh[128 * T_STR];
    __shared__ __align__(16) unsigned short sAl[128 * T_STR];
    __shared__ __align__(16) unsigned short sBh[64 * T_STR];
    __shared__ __align__(16) unsigned short sBl[64 * T_STR];

    const int tid  = threadIdx.x;
    const int lane = tid & 63;
    const int w    = tid >> 6;
    const int q15  = lane & 15;
    const int quad = lane >> 4;
    const int n0b = blockIdx.x * 64;
    const int m0b = blockIdx.y * 128;
    const int wm = (w >> 1) * 64;
    const int wn = (w & 1) * 32;

    const int ar0 = tid >> 2, aks0 = (tid & 3) * 8;
    const int ar1 = (tid + 256) >> 2, aks1 = aks0;
    const int br = tid >> 2, bks = (tid & 3) * 8;

    const unsigned short* gAh0 = Ah + (size_t)(m0b + ar0) * 1024 + aks0;
    const unsigned short* gAh1 = Ah + (size_t)(m0b + ar1) * 1024 + aks1;
    const unsigned short* gAl0 = Al + (size_t)(m0b + ar0) * 1024 + aks0;
    const unsigned short* gAl1 = Al + (size_t)(m0b + ar1) * 1024 + aks1;
    const unsigned short* gBh = Bh + (size_t)(n0b + br) * 1024 + bks;
    const unsigned short* gBl = Bl + (size_t)(n0b + br) * 1024 + bks;

    f32x4 acc[4][2];
#pragma unroll
    for (int mt = 0; mt < 4; ++mt)
#pragma unroll
        for (int nt = 0; nt < 2; ++nt) acc[mt][nt] = (f32x4){0.f, 0.f, 0.f, 0.f};

#pragma unroll 1
    for (int k0 = 0; k0 < 1024; k0 += 32) {
        const bf16x8 vah0 = *(const bf16x8*)(gAh0 + k0);
        const bf16x8 vah1 = *(const bf16x8*)(gAh1 + k0);
        const bf16x8 val0 = *(const bf16x8*)(gAl0 + k0);
        const bf16x8 val1 = *(const bf16x8*)(gAl1 + k0);
        const bf16x8 vbh  = *(const bf16x8*)(gBh + k0);
        const bf16x8 vbl  = *(const bf16x8*)(gBl + k0);
        __syncthreads();
        *(bf16x8*)(sAh + ar0 * T_STR + aks0) = vah0;
        *(bf16x8*)(sAh + ar1 * T_STR + aks1) = vah1;
        *(bf16x8*)(sAl + ar0 * T_STR + aks0) = val0;
        *(bf16x8*)(sAl + ar1 * T_STR + aks1) = val1;
        *(bf16x8*)(sBh + br * T_STR + bks) = vbh;
        *(bf16x8*)(sBl + br * T_STR + bks) = vbl;
        __syncthreads();

        bf16x8 fbh[2], fbl[2];
#pragma unroll
        for (int nt = 0; nt < 2; ++nt) {
            fbh[nt] = *(const bf16x8*)(sBh + (wn + nt * 16 + q15) * T_STR + quad * 8);
            fbl[nt] = *(const bf16x8*)(sBl + (wn + nt * 16 + q15) * T_STR + quad * 8);
        }
#pragma unroll
        for (int mt = 0; mt < 4; ++mt) {
            const bf16x8 fah = *(const bf16x8*)(sAh + (wm + mt * 16 + q15) * T_STR + quad * 8);
            const bf16x8 fal = *(const bf16x8*)(sAl + (wm + mt * 16 + q15) * T_STR + quad * 8);
#pragma unroll
            for (int nt = 0; nt < 2; ++nt) {
                acc[mt][nt] = __builtin_amdgcn_mfma_f32_16x16x32_bf16(fah, fbh[nt], acc[mt][nt], 0, 0, 0);
                acc[mt][nt] = __builtin_amdgcn_mfma_f32_16x16x32_bf16(fah, fbl[nt], acc[mt][nt], 0, 0, 0);
                acc[mt][nt] = __builtin_amdgcn_mfma_f32_16x16x32_bf16(fal, fbh[nt], acc[mt][nt], 0, 0, 0);
            }
        }
    }

#pragma unroll
    for (int nt = 0; nt < 2; ++nt) {
        const int n = n0b + wn + nt * 16 + q15;
        const float bv = bias[n];
#pragma unroll
        for (int mt = 0; mt < 4; ++mt) {
            const int mb = m0b + wm + mt * 16 + quad * 4;
#pragma unroll
            for (int rg = 0; rg < 4; ++rg) {
                const int m = mb + rg;
                const float o = acc[mt][nt][rg] + bv;
                if (mode == 0) {
                    ((float*)out0)[(size_t)m * 1024 + n] = o;
                } else {
                    const int b = m >> 11, s = m & 2047;
                    const int h = n >> 6, hd = n & 63;
                    const size_t base = ((size_t)((b * NH + h) * S_LEN + s)) * HDIM + hd;
                    if (mode == 3) {
                        ((unsigned short*)out0)[base] = f2bf(o);
                    } else {
                        const unsigned short oh = f2bf(o);
                        ((unsigned short*)out0)[base] = oh;
                        ((unsigned short*)out1)[base] = f2bf(o - bf2f(oh));
                    }
                }
            }
        }
    }
}

// ---------------------------------------------------------------------------
// V bf16 [bh][s][64] -> Vt bf16 [bh][64][2048]  (B-operand layout for PV MFMA)
// ---------------------------------------------------------------------------
__global__ __launch_bounds__(256)
void transpose_v16(const unsigned short* __restrict__ V, unsigned short* __restrict__ Vt)
{
    __shared__ unsigned short t[64][72];
    const int tid = threadIdx.x;
    const int s0 = blockIdx.x * 64;
    const int bh = blockIdx.y;
    const unsigned short* Vb = V + (size_t)bh * S_LEN * HDIM;
#pragma unroll
    for (int i = 0; i < 4; ++i) {
        const int f = tid + i * 256;
        const int s = f >> 4;
        const int hq = (f & 15) * 4;
        const ushort4 v = *(const ushort4*)(Vb + (size_t)(s0 + s) * HDIM + hq);
        t[s][hq + 0] = v.x; t[s][hq + 1] = v.y; t[s][hq + 2] = v.z; t[s][hq + 3] = v.w;
    }
    __syncthreads();
    unsigned short* Vtb = Vt + (size_t)bh * HDIM * S_LEN;
#pragma unroll
    for (int i = 0; i < 4; ++i) {
        const int f = tid + i * 256;
        const int hd = f >> 4;
        const int sq = (f & 15) * 4;
        ushort4 v;
        v.x = t[sq + 0][hd]; v.y = t[sq + 1][hd];
        v.z = t[sq + 2][hd]; v.w = t[sq + 3][hd];
        *(ushort4*)(Vtb + (size_t)hd * S_LEN + s0 + sq) = v;
    }
}

// ---------------------------------------------------------------------------
// Exact 409th-largest over 2048 ordered uints held as u[32] per lane.
// Rank-count binary search (R10 version — passing, bit-exact keep set).
// ---------------------------------------------------------------------------
__device__ __forceinline__ unsigned radix_select(const unsigned (&u)[32])
{
    unsigned T = 0;
#pragma unroll 1
    for (int b = 31; b >= 0; --b) {
        const unsigned X = T | (1u << b);
        int cnt = 0;
#pragma unroll
        for (int i = 0; i < 32; ++i)
            cnt += __builtin_popcountll(__ballot(u[i] >= X));
        if (cnt >= KK) {
            T = X;
            if (cnt == KK) {   // answer = min over {u >= X}
                unsigned mn = 0xffffffffu;
#pragma unroll
                for (int i = 0; i < 32; ++i) {
                    const unsigned v = (u[i] >= X) ? u[i] : 0xffffffffu;
                    mn = v < mn ? v : mn;
                }
#pragma unroll
                for (int off = 32; off >= 1; off >>= 1) {
                    const unsigned o = (unsigned)__shfl_xor((int)mn, off);
                    mn = o < mn ? o : mn;
                }
                return mn;
            }
        }
    }
    return T;
}

// ---------------------------------------------------------------------------
// Fused attention v9: 512 threads / 8 waves; block = (bh, 8 q-rows);
// ONE q-row per wave (R9/R10 family — no spill, passing). LDS shrunk to
// 65,792 B -> TWO blocks/CU so independent blocks run out of phase:
// one block's select (VALU) overlaps the other's scores (MFMA+L2).
// Score MFMA B-operand uses 8 of 16 q-cols (row-7 clamp for lanes 8-15;
// garbage cols never written) — per-score values bit-identical to R9/R10.
//  phase 1: wave w computes score cols [256w,256w+256) for the 8 q-rows
//           (16 tiles x 6 split-bf16 MFMA) -> sc[8][2056] f32.
//  barrier; wave w reads row w into u[32]; barrier (sc dead).
//  phase 2: per-wave rank-count select + exp -> P bf16 row w.
//  barrier; phase 3: wave w PV for keys [256w,+256) over 8 q (32 MFMA)
//           -> Opart[w]; barrier; 8-way reduce, bf16 hi/lo out.
// LDS 65,792 B: sc[8][2056]f32 overlaid by P[8][2064]bf16 (33,024 B) +
// Opart[8][8][64]f32 (16,384 B at offset 33,024) — disjoint, 4 barriers.
// ---------------------------------------------------------------------------
__global__ __launch_bounds__(512, 4)
void attn_kernel(const unsigned short* __restrict__ Qh, const unsigned short* __restrict__ Ql,
                 const unsigned short* __restrict__ Kh, const unsigned short* __restrict__ Kl,
                 const unsigned short* __restrict__ Vt,
                 unsigned short* __restrict__ AOh, unsigned short* __restrict__ AOl)
{
    extern __shared__ __align__(16) char smem[];
    float* sc = (float*)smem;                            // [8][SC_STRW] f32
    unsigned short* P = (unsigned short*)smem;           // overlay [8][P_STR] bf16
    float* Opart = (float*)(smem + 33024);               // [8][8][64] f32

    const int tid  = threadIdx.x;
    const int lane = tid & 63;
    const int w    = tid >> 6;        // wave id (0..7) == owned q-row
    const int q15  = lane & 15;
    const int quad = lane >> 4;
    const int qr   = q15 < 8 ? q15 : 7;   // clamped q index for 8-row block

    // XCD swizzle: each XCD works one head at a time -> ~1.75 MB, L2-resident.
    const int blk = blockIdx.x;            // 0..8191
    const int xcd = blk & 7;
    const int j   = blk >> 3;              // 0..1023
    const int bh  = xcd * 4 + (j >> 8);    // 0..31
    const int q0  = (j & 255) * 8;         // 0..2040

    // ---- Q B-frags direct from global (rows 8-15 duplicate row 7) ----
    const size_t qrow = ((size_t)bh * S_LEN + q0 + qr) * HDIM;
    const bf16x8 bqh0 = *(const bf16x8*)(Qh + qrow + quad * 8);
    const bf16x8 bqh1 = *(const bf16x8*)(Qh + qrow + 32 + quad * 8);
    const bf16x8 bql0 = *(const bf16x8*)(Ql + qrow + quad * 8);
    const bf16x8 bql1 = *(const bf16x8*)(Ql + qrow + 32 + quad * 8);

    const size_t kbase = (size_t)bh * S_LEN * HDIM;

    // ---- phase 1: scores for key-span [256w, 256w+256), 8 q-rows ----
#pragma unroll 2
    for (int t = 0; t < 16; ++t) {
        const int key = w * 256 + t * 16 + q15;            // A-frag m
        const unsigned short* kh = Kh + kbase + (size_t)key * HDIM + quad * 8;
        const unsigned short* kl = Kl + kbase + (size_t)key * HDIM + quad * 8;
        const bf16x8 akh0 = *(const bf16x8*)(kh);
        const bf16x8 akh1 = *(const bf16x8*)(kh + 32);
        const bf16x8 akl0 = *(const bf16x8*)(kl);
        const bf16x8 akl1 = *(const bf16x8*)(kl + 32);
        f32x4 c = {0.f, 0.f, 0.f, 0.f};
        c = __builtin_amdgcn_mfma_f32_16x16x32_bf16(akh0, bqh0, c, 0, 0, 0);
        c = __builtin_amdgcn_mfma_f32_16x16x32_bf16(akh1, bqh1, c, 0, 0, 0);
        c = __builtin_amdgcn_mfma_f32_16x16x32_bf16(akh0, bql0, c, 0, 0, 0);
        c = __builtin_amdgcn_mfma_f32_16x16x32_bf16(akh1, bql1, c, 0, 0, 0);
        c = __builtin_amdgcn_mfma_f32_16x16x32_bf16(akl0, bqh0, c, 0, 0, 0);
        c = __builtin_amdgcn_mfma_f32_16x16x32_bf16(akl1, bqh1, c, 0, 0, 0);
        // C-layout: col(lane&15)=q (only 0..7 valid), row(quad*4+reg)=key
        if (q15 < 8)
            *(f32x4*)(sc + q15 * SC_STRW + w * 256 + t * 16 + quad * 4) = c * 0.125f;
    }
    __syncthreads();   // barrier 1: all sc written

    // ---- wave w loads ITS row w (bank=(8w+lane)%32 -> 2-way, free) ----
    unsigned u[32];
#pragma unroll
    for (int i = 0; i < 32; ++i) u[i] = f2ord(sc[w * SC_STRW + i * 64 + lane]);
    __syncthreads();   // barrier 2: sc dead everywhere -> P region reusable

    // ---- phase 2: exact select + softmax numerators -> P row w ----
    const unsigned T = radix_select(u);
    unsigned umx = 0;
#pragma unroll
    for (int i = 0; i < 32; ++i) umx = u[i] > umx ? u[i] : umx;
#pragma unroll
    for (int off = 32; off >= 1; off >>= 1) {
        const unsigned o = (unsigned)__shfl_xor((int)umx, off);
        umx = o > umx ? o : umx;
    }
    const float mx = ord2f(umx);
    float lsum = 0.f;
    unsigned short* Pr = P + w * P_STR;
#pragma unroll
    for (int i = 0; i < 32; ++i) {
        const float e = (u[i] >= T) ? __expf(ord2f(u[i]) - mx) : 0.f;
        Pr[i * 64 + lane] = f2bf(e);
        lsum += e;
    }
#pragma unroll
    for (int off = 32; off >= 1; off >>= 1) lsum += __shfl_xor(lsum, off);
    const float invd = 1.f / lsum;
    __syncthreads();   // barrier 3: all P rows visible

    // ---- phase 3: PV for keys [256w,+256), 8 q-rows (A m-rows 8-15
    //      read clamped row 7; their D rows are never written) ----
    {
        f32x4 oacc[4];
#pragma unroll
        for (int ht = 0; ht < 4; ++ht) oacc[ht] = (f32x4){0.f, 0.f, 0.f, 0.f};
        const size_t vtb = (size_t)bh * HDIM * S_LEN;
#pragma unroll
        for (int ks = 0; ks < 8; ++ks) {
            const int key0 = w * 256 + ks * 32 + quad * 8;
            const bf16x8 ap = *(const bf16x8*)(P + qr * P_STR + key0);    // A[m=q][k]
#pragma unroll
            for (int ht = 0; ht < 4; ++ht) {
                const int hd = ht * 16 + q15;                             // B[k][n=hd]
                const bf16x8 bv = *(const bf16x8*)(Vt + vtb + (size_t)hd * S_LEN + key0);
                oacc[ht] = __builtin_amdgcn_mfma_f32_16x16x32_bf16(ap, bv, oacc[ht], 0, 0, 0);
            }
        }
        // D[m=q][n=hd]: row=quad*4+reg=q (valid 0..7 -> quad<2), col=hd
        if (quad < 2) {
#pragma unroll
            for (int ht = 0; ht < 4; ++ht)
#pragma unroll
                for (int rg = 0; rg < 4; ++rg)
                    Opart[w * 512 + (quad * 4 + rg) * 64 + ht * 16 + q15] = oacc[ht][rg];
        }
    }
    __syncthreads();   // barrier 4: all partials visible

    // ---- final: thread (r=w, hd=lane) reduces 8 partials of row w ----
    {
        float s = 0.f;
#pragma unroll
        for (int ww = 0; ww < 8; ++ww) s += Opart[ww * 512 + w * 64 + lane];
        const float o = s * invd;   // invd belongs to row w == this wave
        const int b = bh >> 4, h = bh & 15;
        const size_t idx = ((size_t)(b * S_LEN + q0 + w)) * DMODEL + h * HDIM + lane;
        const unsigned short hh = f2bf(o);
        AOh[idx] = hh;
        AOl[idx] = f2bf(o - bf2f(hh));
    }
}

// ---------------------------------------------------------------------------
extern "C" void kernel_launch(void* const* d_in, const int* in_sizes, int n_in,
                              void* d_out, int out_size, void* d_ws, size_t ws_size,
                              hipStream_t stream)
{
    const float* X  = (const float*)d_in[0];
    const float* Wq = (const float*)d_in[1];
    const float* bq = (const float*)d_in[2];
    const float* Wk = (const float*)d_in[3];
    const float* bk = (const float*)d_in[4];
    const float* Wv = (const float*)d_in[5];
    const float* bv = (const float*)d_in[6];
    const float* Wo = (const float*)d_in[7];
    const float* bo = (const float*)d_in[8];

    char* p = (char*)d_ws;
    const size_t NEL = (size_t)BHC * S_LEN * HDIM;   // 4,194,304
    unsigned short* Q16h = (unsigned short*)p; p += NEL * 2;
    unsigned short* Q16l = (unsigned short*)p; p += NEL * 2;
    unsigned short* K16h = (unsigned short*)p; p += NEL * 2;
    unsigned short* K16l = (unsigned short*)p; p += NEL * 2;
    unsigned short* Vb16 = (unsigned short*)p; p += NEL * 2;
    unsigned short* Vt16 = (unsigned short*)p; p += NEL * 2;
    unsigned short* Xh   = (unsigned short*)p; p += NEL * 2;
    unsigned short* Xl   = (unsigned short*)p; p += NEL * 2;
    unsigned short* AOh  = (unsigned short*)p; p += NEL * 2;
    unsigned short* AOl  = (unsigned short*)p; p += NEL * 2;
    unsigned short* Wqh  = (unsigned short*)p; p += DMODEL * DMODEL * 2;
    unsigned short* Wql  = (unsigned short*)p; p += DMODEL * DMODEL * 2;
    unsigned short* Wkh  = (unsigned short*)p; p += DMODEL * DMODEL * 2;
    unsigned short* Wkl  = (unsigned short*)p; p += DMODEL * DMODEL * 2;
    unsigned short* Wvh  = (unsigned short*)p; p += DMODEL * DMODEL * 2;
    unsigned short* Wvl  = (unsigned short*)p; p += DMODEL * DMODEL * 2;
    unsigned short* Woh  = (unsigned short*)p; p += DMODEL * DMODEL * 2;
    unsigned short* Wol  = (unsigned short*)p; p += DMODEL * DMODEL * 2;

    const int attn_lds = 8 * SC_STRW * 4;   // 65,792 B -> 2 blocks/CU
    hipFuncSetAttribute((const void*)attn_kernel,
                        hipFuncAttributeMaxDynamicSharedMemorySize, attn_lds);

    const int X4 = (int)(NEL / 4);                 // 1,048,576
    const int W4 = DMODEL * DMODEL / 4;            //   262,144

    // ---- input splits ----
    split32<<<(X4 + 255) / 256, 256, 0, stream>>>(X,  Xh,  Xl,  X4);
    split32<<<(W4 + 255) / 256, 256, 0, stream>>>(Wq, Wqh, Wql, W4);
    split32<<<(W4 + 255) / 256, 256, 0, stream>>>(Wk, Wkh, Wkl, W4);
    split32<<<(W4 + 255) / 256, 256, 0, stream>>>(Wv, Wvh, Wvl, W4);
    split32<<<(W4 + 255) / 256, 256, 0, stream>>>(Wo, Woh, Wol, W4);

    // ---- projections (LDS-staged MFMA split-bf16): tiles 128m x 64n ----
    const dim3 ggrid(16, 32, 1);
    gemm_mfma<<<ggrid, 256, 0, stream>>>(Xh, Xl, Wqh, Wql, bq, Q16h, Q16l, 2);
    gemm_mfma<<<ggrid, 256, 0, stream>>>(Xh, Xl, Wkh, Wkl, bk, K16h, K16l, 2);
    gemm_mfma<<<ggrid, 256, 0, stream>>>(Xh, Xl, Wvh, Wvl, bv, Vb16, nullptr, 3);
    transpose_v16<<<dim3(32, 32, 1), 256, 0, stream>>>(Vb16, Vt16);

    // ---- fused attention v9 (8-row blocks, 2 blocks/CU phase overlap) ----
    attn_kernel<<<8192, 512, attn_lds, stream>>>(Q16h, Q16l, K16h, K16l, Vt16, AOh, AOl);

    // ---- output projection ----
    gemm_mfma<<<ggrid, 256, 0, stream>>>(AOh, AOl, Woh, Wol, bo, d_out, nullptr, 0);
}

// Round 12
// 859.071 us; speedup vs baseline: 1.3030x; 1.3030x over previous
//
#include <hip/hip_runtime.h>
#include <math.h>

#define S_LEN 2048
#define NH 16
#define HDIM 64
#define BATCH 2
#define BHC 32          // BATCH*NH
#define KK 409          // int(2048 * (1.0 - 0.8)) per reference float math
#define DMODEL 1024

typedef __attribute__((ext_vector_type(8))) short bf16x8;   // 8 bf16 in 4 VGPRs
typedef __attribute__((ext_vector_type(4))) float f32x4;

#define SC_STR 1032     // fp32 half-score row stride (chunked exchange)
#define P_STR  2056     // bf16 P row stride (16B-aligned rows)
#define T_STR  40       // bf16 LDS tile row stride: 80 B, 16B-aligned, 2-way free

__device__ __forceinline__ unsigned f2ord(float f) {
    unsigned u = __float_as_uint(f);
    return (u & 0x80000000u) ? ~u : (u | 0x80000000u);
}
__device__ __forceinline__ float ord2f(unsigned v) {
    unsigned u = (v & 0x80000000u) ? (v & 0x7fffffffu) : ~v;
    return __uint_as_float(u);
}
__device__ __forceinline__ unsigned short f2bf(float f) {   // RNE
    unsigned u = __float_as_uint(f);
    u += 0x7fffu + ((u >> 16) & 1u);
    return (unsigned short)(u >> 16);
}
__device__ __forceinline__ float bf2f(unsigned short h) {
    return __uint_as_float(((unsigned)h) << 16);
}

// ---------------------------------------------------------------------------
// fp32 -> bf16 hi/lo split (vectorized float4 / ushort4), n4 = elements/4
// ---------------------------------------------------------------------------
__global__ __launch_bounds__(256)
void split32(const float* __restrict__ in, unsigned short* __restrict__ hi,
             unsigned short* __restrict__ lo, int n4)
{
    const int i = blockIdx.x * 256 + threadIdx.x;
    if (i < n4) {
        const float4 v = ((const float4*)in)[i];
        ushort4 h, l;
        h.x = f2bf(v.x); l.x = f2bf(v.x - bf2f(h.x));
        h.y = f2bf(v.y); l.y = f2bf(v.y - bf2f(h.y));
        h.z = f2bf(v.z); l.z = f2bf(v.z - bf2f(h.z));
        h.w = f2bf(v.w); l.w = f2bf(v.w - bf2f(h.w));
        ((ushort4*)hi)[i] = h;
        ((ushort4*)lo)[i] = l;
    }
}

// ---------------------------------------------------------------------------
// LDS-staged split-bf16 3-pass MFMA GEMM (R8 — banked).
//   C[m][n] = sum_k A[m][k]*B[n][k] + bias[n]
// ---------------------------------------------------------------------------
__global__ __launch_bounds__(256)
void gemm_mfma(const unsigned short* __restrict__ Ah, const unsigned short* __restrict__ Al,
               const unsigned short* __restrict__ Bh, const unsigned short* __restrict__ Bl,
               const float* __restrict__ bias, void* __restrict__ out0,
               void* __restrict__ out1, int mode)
{
    __shared__ __align__(16) unsigned short sAh[128 * T_STR];
    __shared__ __align__(16) unsigned short sAl[128 * T_STR];
    __shared__ __align__(16) unsigned short sBh[64 * T_STR];
    __shared__ __align__(16) unsigned short sBl[64 * T_STR];

    const int tid  = threadIdx.x;
    const int lane = tid & 63;
    const int w    = tid >> 6;
    const int q15  = lane & 15;
    const int quad = lane >> 4;
    const int n0b = blockIdx.x * 64;
    const int m0b = blockIdx.y * 128;
    const int wm = (w >> 1) * 64;
    const int wn = (w & 1) * 32;

    const int ar0 = tid >> 2, aks0 = (tid & 3) * 8;
    const int ar1 = (tid + 256) >> 2, aks1 = aks0;
    const int br = tid >> 2, bks = (tid & 3) * 8;

    const unsigned short* gAh0 = Ah + (size_t)(m0b + ar0) * 1024 + aks0;
    const unsigned short* gAh1 = Ah + (size_t)(m0b + ar1) * 1024 + aks1;
    const unsigned short* gAl0 = Al + (size_t)(m0b + ar0) * 1024 + aks0;
    const unsigned short* gAl1 = Al + (size_t)(m0b + ar1) * 1024 + aks1;
    const unsigned short* gBh = Bh + (size_t)(n0b + br) * 1024 + bks;
    const unsigned short* gBl = Bl + (size_t)(n0b + br) * 1024 + bks;

    f32x4 acc[4][2];
#pragma unroll
    for (int mt = 0; mt < 4; ++mt)
#pragma unroll
        for (int nt = 0; nt < 2; ++nt) acc[mt][nt] = (f32x4){0.f, 0.f, 0.f, 0.f};

#pragma unroll 1
    for (int k0 = 0; k0 < 1024; k0 += 32) {
        const bf16x8 vah0 = *(const bf16x8*)(gAh0 + k0);
        const bf16x8 vah1 = *(const bf16x8*)(gAh1 + k0);
        const bf16x8 val0 = *(const bf16x8*)(gAl0 + k0);
        const bf16x8 val1 = *(const bf16x8*)(gAl1 + k0);
        const bf16x8 vbh  = *(const bf16x8*)(gBh + k0);
        const bf16x8 vbl  = *(const bf16x8*)(gBl + k0);
        __syncthreads();
        *(bf16x8*)(sAh + ar0 * T_STR + aks0) = vah0;
        *(bf16x8*)(sAh + ar1 * T_STR + aks1) = vah1;
        *(bf16x8*)(sAl + ar0 * T_STR + aks0) = val0;
        *(bf16x8*)(sAl + ar1 * T_STR + aks1) = val1;
        *(bf16x8*)(sBh + br * T_STR + bks) = vbh;
        *(bf16x8*)(sBl + br * T_STR + bks) = vbl;
        __syncthreads();

        bf16x8 fbh[2], fbl[2];
#pragma unroll
        for (int nt = 0; nt < 2; ++nt) {
            fbh[nt] = *(const bf16x8*)(sBh + (wn + nt * 16 + q15) * T_STR + quad * 8);
            fbl[nt] = *(const bf16x8*)(sBl + (wn + nt * 16 + q15) * T_STR + quad * 8);
        }
#pragma unroll
        for (int mt = 0; mt < 4; ++mt) {
            const bf16x8 fah = *(const bf16x8*)(sAh + (wm + mt * 16 + q15) * T_STR + quad * 8);
            const bf16x8 fal = *(const bf16x8*)(sAl + (wm + mt * 16 + q15) * T_STR + quad * 8);
#pragma unroll
            for (int nt = 0; nt < 2; ++nt) {
                acc[mt][nt] = __builtin_amdgcn_mfma_f32_16x16x32_bf16(fah, fbh[nt], acc[mt][nt], 0, 0, 0);
                acc[mt][nt] = __builtin_amdgcn_mfma_f32_16x16x32_bf16(fah, fbl[nt], acc[mt][nt], 0, 0, 0);
                acc[mt][nt] = __builtin_amdgcn_mfma_f32_16x16x32_bf16(fal, fbh[nt], acc[mt][nt], 0, 0, 0);
            }
        }
    }

#pragma unroll
    for (int nt = 0; nt < 2; ++nt) {
        const int n = n0b + wn + nt * 16 + q15;
        const float bv = bias[n];
#pragma unroll
        for (int mt = 0; mt < 4; ++mt) {
            const int mb = m0b + wm + mt * 16 + quad * 4;
#pragma unroll
            for (int rg = 0; rg < 4; ++rg) {
                const int m = mb + rg;
                const float o = acc[mt][nt][rg] + bv;
                if (mode == 0) {
                    ((float*)out0)[(size_t)m * 1024 + n] = o;
                } else {
                    const int b = m >> 11, s = m & 2047;
                    const int h = n >> 6, hd = n & 63;
                    const size_t base = ((size_t)((b * NH + h) * S_LEN + s)) * HDIM + hd;
                    if (mode == 3) {
                        ((unsigned short*)out0)[base] = f2bf(o);
                    } else {
                        const unsigned short oh = f2bf(o);
                        ((unsigned short*)out0)[base] = oh;
                        ((unsigned short*)out1)[base] = f2bf(o - bf2f(oh));
                    }
                }
            }
        }
    }
}

// ---------------------------------------------------------------------------
// V bf16 [bh][s][64] -> Vt bf16 [bh][64][2048]  (B-operand layout for PV MFMA)
// ---------------------------------------------------------------------------
__global__ __launch_bounds__(256)
void transpose_v16(const unsigned short* __restrict__ V, unsigned short* __restrict__ Vt)
{
    __shared__ unsigned short t[64][72];
    const int tid = threadIdx.x;
    const int s0 = blockIdx.x * 64;
    const int bh = blockIdx.y;
    const unsigned short* Vb = V + (size_t)bh * S_LEN * HDIM;
#pragma unroll
    for (int i = 0; i < 4; ++i) {
        const int f = tid + i * 256;
        const int s = f >> 4;
        const int hq = (f & 15) * 4;
        const ushort4 v = *(const ushort4*)(Vb + (size_t)(s0 + s) * HDIM + hq);
        t[s][hq + 0] = v.x; t[s][hq + 1] = v.y; t[s][hq + 2] = v.z; t[s][hq + 3] = v.w;
    }
    __syncthreads();
    unsigned short* Vtb = Vt + (size_t)bh * HDIM * S_LEN;
#pragma unroll
    for (int i = 0; i < 4; ++i) {
        const int f = tid + i * 256;
        const int hd = f >> 4;
        const int sq = (f & 15) * 4;
        ushort4 v;
        v.x = t[sq + 0][hd]; v.y = t[sq + 1][hd];
        v.z = t[sq + 2][hd]; v.w = t[sq + 3][hd];
        *(ushort4*)(Vtb + (size_t)hd * S_LEN + s0 + sq) = v;
    }
}

// ---------------------------------------------------------------------------
// Exact 409th-largest over 2048 ordered uints held as u[32] per lane.
// RANK-COUNT binary search (R10-proven): per bit ONE v_cmp per element
// (uniform threshold; ballot+popcount on SALU). If #{u>=X} >= K the bit is
// set. Early exit at cnt==K: answer = min over {u >= X}. Keep set {u >= T}
// includes ties — matches reference `attn < thr` masking exactly.
// (Runtime-pointer arg preserved from R8's passing structure.)
// ---------------------------------------------------------------------------
__device__ __forceinline__ unsigned radix_select(const unsigned* u)
{
    unsigned T = 0;
#pragma unroll 1
    for (int b = 31; b >= 0; --b) {
        const unsigned X = T | (1u << b);
        int cnt = 0;
#pragma unroll
        for (int i = 0; i < 32; ++i)
            cnt += __builtin_popcountll(__ballot(u[i] >= X));
        if (cnt >= KK) {
            T = X;
            if (cnt == KK) {   // answer = min over {u >= X}
                unsigned mn = 0xffffffffu;
#pragma unroll
                for (int i = 0; i < 32; ++i) {
                    const unsigned v = (u[i] >= X) ? u[i] : 0xffffffffu;
                    mn = v < mn ? v : mn;
                }
#pragma unroll
                for (int off = 32; off >= 1; off >>= 1) {
                    const unsigned o = (unsigned)__shfl_xor((int)mn, off);
                    mn = o < mn ? o : mn;
                }
                return mn;
            }
        }
    }
    return T;
}

// ---------------------------------------------------------------------------
// Fused attention — R8 structure (thrice-passing: R5/R7/R8) with two
// evidence-backed upgrades only:
//  * rank-count select (R10-proven, -VALU)
//  * vectorized score exchange: u-read 4x ds_read_b128/row-half (contiguous
//    cols), P-write 8x ds_write_b64/row.  Key mapping (bijective):
//      u[h*16+4i+cc]  <->  key = (2i + (lane>>5))*256 + h*128 + (lane&31)*4 + cc
// DO NOT make u0/u1 register-resident (R6 failed post-timing validation).
// Known cost: u0/u1 live in scratch (~0.7 GB FETCH) — proven NOT the limiter
// (R9 removed it and got slower).
// ---------------------------------------------------------------------------
__global__ __launch_bounds__(512, 4)
void attn_kernel(const unsigned short* __restrict__ Qh, const unsigned short* __restrict__ Ql,
                 const unsigned short* __restrict__ Kh, const unsigned short* __restrict__ Kl,
                 const unsigned short* __restrict__ Vt,
                 unsigned short* __restrict__ AOh, unsigned short* __restrict__ AOl)
{
    extern __shared__ __align__(16) char smem[];
    float* sc = (float*)smem;                       // [16][SC_STR] chunk, 66048 B
    unsigned short* P = (unsigned short*)smem;      // overlay [16][P_STR], 65792 B
    float* Opart = (float*)smem;                    // overlay [8][16][64], 32768 B

    const int tid  = threadIdx.x;
    const int lane = tid & 63;
    const int w    = tid >> 6;
    const int q15  = lane & 15;
    const int quad = lane >> 4;
    const int l5   = lane >> 5;       // 0..1
    const int l31  = lane & 31;       // 0..31

    // XCD swizzle: 4 heads per XCD -> K+V working set ~2.5 MB, fits 4 MB L2
    const int blk = blockIdx.x;
    const int bh  = (blk & 7) * 4 + ((blk >> 3) & 3);
    const int q0  = (blk >> 5) * 16;

    // ---- Q B-frags direct from global (held in regs for both chunks) ----
    const size_t qrow = ((size_t)bh * S_LEN + q0 + q15) * HDIM;
    const bf16x8 bqh0 = *(const bf16x8*)(Qh + qrow + quad * 8);
    const bf16x8 bqh1 = *(const bf16x8*)(Qh + qrow + 32 + quad * 8);
    const bf16x8 bql0 = *(const bf16x8*)(Ql + qrow + quad * 8);
    const bf16x8 bql1 = *(const bf16x8*)(Ql + qrow + 32 + quad * 8);

    const size_t kbase = (size_t)bh * S_LEN * HDIM;
    const int r0 = 2 * w, r1 = 2 * w + 1;
    unsigned u0[32], u1[32];

    // ---- phase 1: two key-chunks through the half-size exchange buffer ----
#pragma unroll 1
    for (int half = 0; half < 2; ++half) {
        f32x4 acc[8];
#pragma unroll 2
        for (int t = 0; t < 8; ++t) {
            const int key = w * 256 + half * 128 + t * 16 + q15;   // A-frag m
            const unsigned short* kh = Kh + kbase + (size_t)key * HDIM + quad * 8;
            const unsigned short* kl = Kl + kbase + (size_t)key * HDIM + quad * 8;
            const bf16x8 akh0 = *(const bf16x8*)(kh);
            const bf16x8 akh1 = *(const bf16x8*)(kh + 32);
            const bf16x8 akl0 = *(const bf16x8*)(kl);
            const bf16x8 akl1 = *(const bf16x8*)(kl + 32);
            f32x4 c = {0.f, 0.f, 0.f, 0.f};
            c = __builtin_amdgcn_mfma_f32_16x16x32_bf16(akh0, bqh0, c, 0, 0, 0);
            c = __builtin_amdgcn_mfma_f32_16x16x32_bf16(akh1, bqh1, c, 0, 0, 0);
            c = __builtin_amdgcn_mfma_f32_16x16x32_bf16(akh0, bql0, c, 0, 0, 0);
            c = __builtin_amdgcn_mfma_f32_16x16x32_bf16(akh1, bql1, c, 0, 0, 0);
            c = __builtin_amdgcn_mfma_f32_16x16x32_bf16(akl0, bqh0, c, 0, 0, 0);
            c = __builtin_amdgcn_mfma_f32_16x16x32_bf16(akl1, bqh1, c, 0, 0, 0);
            acc[t] = c * 0.125f;
        }
        if (half) __syncthreads();   // chunk-A reads complete before overwrite
        // C-layout: col=lane&15=q, row-in-tile=quad*4+reg=key
        // sc col c = w*128 + t*16 + quad*4 (+reg)  ->  key = (c>>7)*256 + half*128 + (c&127)
#pragma unroll
        for (int t = 0; t < 8; ++t)
            *(f32x4*)(sc + q15 * SC_STR + w * 128 + t * 16 + quad * 4) = acc[t];
        __syncthreads();
        // vectorized read of both owned rows' half: 4x ds_read_b128 each.
        // u[half*16+4i+cc] <-> key = (2i+l5)*256 + half*128 + l31*4 + cc
        unsigned* d0 = u0 + half * 16;
        unsigned* d1 = u1 + half * 16;
#pragma unroll
        for (int i = 0; i < 4; ++i) {
            const f32x4 v0 = *(const f32x4*)(sc + r0 * SC_STR + i * 256 + lane * 4);
            d0[4 * i + 0] = f2ord(v0[0]); d0[4 * i + 1] = f2ord(v0[1]);
            d0[4 * i + 2] = f2ord(v0[2]); d0[4 * i + 3] = f2ord(v0[3]);
            const f32x4 v1 = *(const f32x4*)(sc + r1 * SC_STR + i * 256 + lane * 4);
            d1[4 * i + 0] = f2ord(v1[0]); d1[4 * i + 1] = f2ord(v1[1]);
            d1[4 * i + 2] = f2ord(v1[2]); d1[4 * i + 3] = f2ord(v1[3]);
        }
    }
    __syncthreads();   // all chunk reads done; sc region is dead -> P region live

    // ---- phase 2: select + softmax numerators -> P (bf16), 2 rows/wave ----
    float invd[2];
#pragma unroll 1
    for (int rr = 0; rr < 2; ++rr) {
        const unsigned* u = rr ? u1 : u0;
        const int r = rr ? r1 : r0;
        const unsigned T = radix_select(u);
        unsigned umx = 0;
#pragma unroll
        for (int i = 0; i < 32; ++i) umx = u[i] > umx ? u[i] : umx;
#pragma unroll
        for (int off = 32; off >= 1; off >>= 1) {
            const unsigned o = (unsigned)__shfl_xor((int)umx, off);
            umx = o > umx ? o : umx;
        }
        const float mx = ord2f(umx);
        float lsum = 0.f;
        unsigned short* Pr = P + r * P_STR;
#pragma unroll
        for (int h = 0; h < 2; ++h) {
#pragma unroll
            for (int i = 0; i < 4; ++i) {
                const unsigned a0 = u[h * 16 + 4 * i + 0];
                const unsigned a1 = u[h * 16 + 4 * i + 1];
                const unsigned a2 = u[h * 16 + 4 * i + 2];
                const unsigned a3 = u[h * 16 + 4 * i + 3];
                const float e0 = (a0 >= T) ? __expf(ord2f(a0) - mx) : 0.f;
                const float e1 = (a1 >= T) ? __expf(ord2f(a1) - mx) : 0.f;
                const float e2 = (a2 >= T) ? __expf(ord2f(a2) - mx) : 0.f;
                const float e3 = (a3 >= T) ? __expf(ord2f(a3) - mx) : 0.f;
                ushort4 pk;
                pk.x = f2bf(e0); pk.y = f2bf(e1); pk.z = f2bf(e2); pk.w = f2bf(e3);
                const int key = (2 * i + l5) * 256 + h * 128 + l31 * 4;
                *(ushort4*)(Pr + key) = pk;   // 8 B ds_write_b64
                lsum += e0 + e1 + e2 + e3;
            }
        }
#pragma unroll
        for (int off = 32; off >= 1; off >>= 1) lsum += __shfl_xor(lsum, off);
        invd[rr] = 1.f / lsum;
    }
    __syncthreads();   // all P visible

    // ---- phase 3: dense PV via bf16 MFMA, wave w keys [256w,256w+256) ----
    {
        f32x4 oacc[4];
#pragma unroll
        for (int ht = 0; ht < 4; ++ht) oacc[ht] = (f32x4){0.f, 0.f, 0.f, 0.f};
        const size_t vtb = (size_t)bh * HDIM * S_LEN;
#pragma unroll 2
        for (int ks = 0; ks < 8; ++ks) {
            const int key0 = w * 256 + ks * 32 + quad * 8;
            const bf16x8 ap = *(const bf16x8*)(P + q15 * P_STR + key0);  // A[m=q][k=key]
#pragma unroll
            for (int ht = 0; ht < 4; ++ht) {
                const int hd = ht * 16 + q15;                            // B[k=key][n=hd]
                const bf16x8 bv = *(const bf16x8*)(Vt + vtb + (size_t)hd * S_LEN + key0);
                oacc[ht] = __builtin_amdgcn_mfma_f32_16x16x32_bf16(ap, bv, oacc[ht], 0, 0, 0);
            }
        }
        __syncthreads();   // all P reads done; P region dead -> Opart live
        // D[m=q][n=hd]: col=lane&15=hd-in-tile, row=quad*4+reg=q
#pragma unroll
        for (int ht = 0; ht < 4; ++ht)
#pragma unroll
            for (int rg = 0; rg < 4; ++rg)
                Opart[w * 1024 + (quad * 4 + rg) * 64 + ht * 16 + q15] = oacc[ht][rg];
    }
    __syncthreads();

    // ---- final: reduce 8 partials, scale, write AO as bf16 hi/lo ----
    {
        float s0 = 0.f, s1 = 0.f;
#pragma unroll
        for (int ww = 0; ww < 8; ++ww) {
            s0 += Opart[ww * 1024 + r0 * 64 + lane];
            s1 += Opart[ww * 1024 + r1 * 64 + lane];
        }
        const int b = bh >> 4, h = bh & 15;
        const float o0 = s0 * invd[0];
        const float o1 = s1 * invd[1];
        const size_t i0 = ((size_t)(b * S_LEN + q0 + r0)) * DMODEL + h * HDIM + lane;
        const size_t i1 = ((size_t)(b * S_LEN + q0 + r1)) * DMODEL + h * HDIM + lane;
        const unsigned short h0 = f2bf(o0), h1 = f2bf(o1);
        AOh[i0] = h0; AOl[i0] = f2bf(o0 - bf2f(h0));
        AOh[i1] = h1; AOl[i1] = f2bf(o1 - bf2f(h1));
    }
}

// ---------------------------------------------------------------------------
extern "C" void kernel_launch(void* const* d_in, const int* in_sizes, int n_in,
                              void* d_out, int out_size, void* d_ws, size_t ws_size,
                              hipStream_t stream)
{
    const float* X  = (const float*)d_in[0];
    const float* Wq = (const float*)d_in[1];
    const float* bq = (const float*)d_in[2];
    const float* Wk = (const float*)d_in[3];
    const float* bk = (const float*)d_in[4];
    const float* Wv = (const float*)d_in[5];
    const float* bv = (const float*)d_in[6];
    const float* Wo = (const float*)d_in[7];
    const float* bo = (const float*)d_in[8];

    char* p = (char*)d_ws;
    const size_t NEL = (size_t)BHC * S_LEN * HDIM;   // 4,194,304
    unsigned short* Q16h = (unsigned short*)p; p += NEL * 2;
    unsigned short* Q16l = (unsigned short*)p; p += NEL * 2;
    unsigned short* K16h = (unsigned short*)p; p += NEL * 2;
    unsigned short* K16l = (unsigned short*)p; p += NEL * 2;
    unsigned short* Vb16 = (unsigned short*)p; p += NEL * 2;
    unsigned short* Vt16 = (unsigned short*)p; p += NEL * 2;
    unsigned short* Xh   = (unsigned short*)p; p += NEL * 2;
    unsigned short* Xl   = (unsigned short*)p; p += NEL * 2;
    unsigned short* AOh  = (unsigned short*)p; p += NEL * 2;
    unsigned short* AOl  = (unsigned short*)p; p += NEL * 2;
    unsigned short* Wqh  = (unsigned short*)p; p += DMODEL * DMODEL * 2;
    unsigned short* Wql  = (unsigned short*)p; p += DMODEL * DMODEL * 2;
    unsigned short* Wkh  = (unsigned short*)p; p += DMODEL * DMODEL * 2;
    unsigned short* Wkl  = (unsigned short*)p; p += DMODEL * DMODEL * 2;
    unsigned short* Wvh  = (unsigned short*)p; p += DMODEL * DMODEL * 2;
    unsigned short* Wvl  = (unsigned short*)p; p += DMODEL * DMODEL * 2;
    unsigned short* Woh  = (unsigned short*)p; p += DMODEL * DMODEL * 2;
    unsigned short* Wol  = (unsigned short*)p; p += DMODEL * DMODEL * 2;

    const int attn_lds = 16 * SC_STR * 4;   // 66,048 B
    hipFuncSetAttribute((const void*)attn_kernel,
                        hipFuncAttributeMaxDynamicSharedMemorySize, attn_lds);

    const int X4 = (int)(NEL / 4);                 // 1,048,576
    const int W4 = DMODEL * DMODEL / 4;            //   262,144

    // ---- input splits ----
    split32<<<(X4 + 255) / 256, 256, 0, stream>>>(X,  Xh,  Xl,  X4);
    split32<<<(W4 + 255) / 256, 256, 0, stream>>>(Wq, Wqh, Wql, W4);
    split32<<<(W4 + 255) / 256, 256, 0, stream>>>(Wk, Wkh, Wkl, W4);
    split32<<<(W4 + 255) / 256, 256, 0, stream>>>(Wv, Wvh, Wvl, W4);
    split32<<<(W4 + 255) / 256, 256, 0, stream>>>(Wo, Woh, Wol, W4);

    // ---- projections (LDS-staged MFMA split-bf16): tiles 128m x 64n ----
    const dim3 ggrid(16, 32, 1);
    gemm_mfma<<<ggrid, 256, 0, stream>>>(Xh, Xl, Wqh, Wql, bq, Q16h, Q16l, 2);
    gemm_mfma<<<ggrid, 256, 0, stream>>>(Xh, Xl, Wkh, Wkl, bk, K16h, K16l, 2);
    gemm_mfma<<<ggrid, 256, 0, stream>>>(Xh, Xl, Wvh, Wvl, bv, Vb16, nullptr, 3);
    transpose_v16<<<dim3(32, 32, 1), 256, 0, stream>>>(Vb16, Vt16);

    // ---- fused attention (R8 structure + rank-count select + vec exchange) ----
    attn_kernel<<<4096, 512, attn_lds, stream>>>(Q16h, Q16l, K16h, K16l, Vt16, AOh, AOl);

    // ---- output projection ----
    gemm_mfma<<<ggrid, 256, 0, stream>>>(AOh, AOl, Woh, Wol, bo, d_out, nullptr, 0);
}